// Round 19
// baseline (252.008 us; speedup 1.0000x reference)
//
#include <hip/hip_runtime.h>
#include <hip/hip_bf16.h>

typedef _Float16 f16;
typedef _Float16 f16x2 __attribute__((ext_vector_type(2)));
typedef _Float16 f16x8 __attribute__((ext_vector_type(8)));
typedef float f32x4 __attribute__((ext_vector_type(4)));

#define B_  4
#define L_  2048
#define D_  4096
#define H_  8
#define BW_ 512
#define M_  (B_*L_)      // 8192
#define CHUNK 128
#define NCH (L_/CHUNK)   // 16
#define LOG2E 1.4426950408889634f

// workspace layout (bytes)
static const size_t OFF_WPK   = 0;                 // packed B frags: 8MB (both gates)
static const size_t OFF_MSP   = 8ull<<20;          // D_ f32, pre-scaled by log2e
static const size_t OFF_XH    = 9ull<<20;          // M*D fp16 = 64MB
static const size_t OFF_YLAP  = 73ull<<20;         // M*D f16x2 (yloc,apfx) = 134MB
static const size_t OFF_SUMA  = 208ull<<20;        // B*NCH*D f32 = 1MB
static const size_t OFF_SUMY  = 209ull<<20;

__device__ __forceinline__ void gl16(const void* g, void* l) {
    __builtin_amdgcn_global_load_lds(
        (const __attribute__((address_space(1))) unsigned int*)g,
        (__attribute__((address_space(3))) unsigned int*)l, 16, 0, 0);
}

// ---------- prep (merged): wpack + msp2 (blocks 0..1023) | x->f16 (1024..3071) ----------
__global__ __launch_bounds__(256)
void prep_all(const float* __restrict__ w_in, const float* __restrict__ w_a,
              const float* __restrict__ a_param, const float* __restrict__ x,
              f16* __restrict__ wpk, float* __restrict__ msp2,
              f16* __restrict__ xh) {
    const int bid = blockIdx.x;
    const int tid = threadIdx.x;
    if (bid < 1024) {
        const int kt  = bid & 7;
        const int n32 = (bid >> 3) & 15;
        const int h   = bid >> 7;
        if (bid < 16) {                    // folded: msp2[d]
            int d = bid * 256 + tid;
            float v = a_param[d];
            msp2[d] = -8.f * log1pf(expf(v)) * LOG2E;
        }
#pragma unroll
        for (int q = 0; q < 2; ++q) {
            int slot = q * 256 + tid;      // 0..511
            int lane = slot & 63;
            int fidx = slot >> 6;          // g*4 + fn*2 + kk2
            int g    = fidx >> 2;
            int fn   = (fidx >> 1) & 1;
            int kk2  = fidx & 1;
            int row = n32 * 32 + fn * 16 + (lane & 15);
            int col = kt * 64 + kk2 * 32 + ((lane >> 4) << 3);
            const float* src = (g ? w_a : w_in) + (size_t)h * BW_ * BW_;
            f16x8 v;
#pragma unroll
            for (int e = 0; e < 8; ++e)
                v[e] = (f16)src[(size_t)(col + e) * BW_ + row];
            size_t o = ((((size_t)(h * 16 + n32) * 8 + kt) * 8) + fidx) * 64 + lane;
            *(f16x8*)(wpk + o * 8) = v;
        }
    } else {
        size_t i = ((size_t)(bid - 1024) * 256 + tid) * 8;
        const size_t stride = (size_t)2048 * 256 * 8;
        for (; i < (size_t)M_ * D_; i += stride) {
            f32x4 v0 = *(const f32x4*)(x + i);
            f32x4 v1 = *(const f32x4*)(x + i + 4);
            f16x8 hv;
            hv[0] = (f16)v0.x; hv[1] = (f16)v0.y; hv[2] = (f16)v0.z; hv[3] = (f16)v0.w;
            hv[4] = (f16)v1.x; hv[5] = (f16)v1.y; hv[6] = (f16)v1.z; hv[7] = (f16)v1.w;
            *(f16x8*)(xh + i) = hv;
        }
    }
}

// ---------- fused gate GEMM + epilogue + chunk-local scan ----------
// BM=128 (= one scan chunk), BN=64, BKK=64, NT=8, EIGHT waves (4 wr x 2 wc),
// 32-row wave tiles: acc = 32 regs/wave (was 64) -> ~87 total regs/wave ->
// 5-6 waves/SIMD occupancy (R16-R18 were pinned at 3 by the 64-reg acc).
// Serial tail also halves per-thread: epilogue 16 elems, scan 8 segs x 16.
// Schedule (R18 form): vmcnt(0) pre-barrier drains A(t) (2 gl16/wave,
// issued at t-1); post-barrier LOAD_B(t) then STAGE_A(t+1) — implicit
// vmcnt(2) before B use keeps A(t+1) flying. Single barrier per tile.
// txo=+1: slot 7 = tile n0>>6 -> buf1 = epilogue xv.
#define BM 128
#define BN 64
#define BKK 64
#define NT (BW_/BKK)     // 8 K-tiles
#define BUFB 16384       // bytes per A staging buffer

// LDS: buf0 @0, buf1 @16384 (32K). Post-loop overlay (over BOTH bufs):
//  axn[128][66] f16x2 {om,xn} @0 (33792) | segA[8][72]f32 @33792 (2304) |
//  segY @36096 (2304) | rst_s[128]f32 @38400 -> 38912
#define SMEM_BYTES 38912

__global__ __launch_bounds__(512, 1)
void gemm_gates(const f16*   __restrict__ xh,
                const int*   __restrict__ segpos,
                const f16*   __restrict__ wpk,
                const float* __restrict__ b_in,
                const float* __restrict__ b_a,
                const float* __restrict__ msp2,
                f16x2* __restrict__ ylap,
                float* __restrict__ sumA,
                float* __restrict__ sumY) {
    __shared__ __align__(16) char smem[SMEM_BYTES];
    f16x2* axn  = (f16x2*)smem;               // [128][66] {om, xn}
    float* segA = (float*)(smem + 33792);     // [8][72]
    float* segY = (float*)(smem + 36096);     // [8][72]
    float* rst_s= (float*)(smem + 38400);     // [128] (outside staging region)

    const int tid  = threadIdx.x;
    const int m0   = blockIdx.x * BM;         // m fastest (R6/R12 grid)
    const int n0   = blockIdx.y * BN;
    const int h    = blockIdx.z;
    const int lane = tid & 63;
    const int wid  = tid >> 6;                // 0..7
    const int wr   = wid >> 1;                // 0..3 (32-row group)
    const int wc   = wid & 1;                 // 0..1 (32-col group)

    f32x4 accX[2][2] = {};
    f32x4 accA[2][2] = {};

    // reset flags -> LDS region untouched by staging
    if (tid < BM) rst_s[tid] = (segpos[m0 + tid] == 0) ? 1.f : 0.f;

    // A staging map: wave wid stages rows [wid*16, wid*16+16) via 2 gl16
    const int grow  = lane >> 3;
    const int gcolS = (((lane & 7) ^ grow) << 3);
    const f16* aSrc = xh + (size_t)(m0 + wid * 16 + grow) * D_ + h * BW_ + gcolS;

    // B packed fragment base for this wave: (h, n32 = n0/32 + wc)
    const f16* wbase = wpk + ((size_t)(h * 16) + (n0 >> 5) + wc) * 32768;

    const int swz  = (lane & 7) << 3;        // read-side XOR (involution)
    const int kx   = (lane >> 4) << 3;       // 0,8,16,24
    const int arow = wr * 32 + (lane & 15);
    const int rowb = wr * 32 + ((lane >> 4) << 2);
    const int txo  = ((n0 >> 6) + 1) & (NT - 1); // slot 7 = tile n0>>6 -> buf1

    f16x8 bfr[8];                             // single-buffered B fragments

#define STAGE_A(T)                                                            \
    {                                                                         \
        const int ktg = ((T) + txo) & (NT - 1);                               \
        f16* Asb = (f16*)(smem + ((T) & 1) * BUFB);                           \
        _Pragma("unroll")                                                     \
        for (int q = 0; q < 2; ++q)                                           \
            gl16(aSrc + ktg * BKK + (size_t)q * 8 * D_,                       \
                 &Asb[(wid * 16 + q * 8) * 64]);                              \
    }
#define LOAD_B(T)                                                             \
    {                                                                         \
        const int ktg = ((T) + txo) & (NT - 1);                               \
        const f16* tp = wbase + (size_t)ktg * 4096;                           \
        _Pragma("unroll")                                                     \
        for (int j = 0; j < 8; ++j)                                           \
            bfr[j] = *(const f16x8*)(tp + j * 512 + lane * 8);                \
    }

    // prologue: A(0) only
    STAGE_A(0);

#pragma unroll
    for (int t = 0; t < NT; ++t) {
        // drain A(t) (issued at t-1 / prologue; one compute phase of cover)
        asm volatile("s_waitcnt vmcnt(0)" ::: "memory");
        __builtin_amdgcn_s_barrier();        // all waves' A(t) visible
        LOAD_B(t);                           // 8 vm -> regs (L2-hot)
        if (t + 1 < NT) STAGE_A(t + 1);      // 2 vm (stays in flight)
        __builtin_amdgcn_sched_barrier(0);   // pin issues before compute

        const f16* Asb = (const f16*)(smem + (t & 1) * BUFB);
#pragma unroll
        for (int kk2 = 0; kk2 < 2; ++kk2) {
            const int kcolS = (kk2 * 32 + kx) ^ swz;
            f16x8 af[2];
#pragma unroll
            for (int fm = 0; fm < 2; ++fm)
                af[fm] = *(const f16x8*)&Asb[(arow + fm * 16) * 64 + kcolS];
#pragma unroll
            for (int fn = 0; fn < 2; ++fn) {
                f16x8 bx = bfr[fn * 2 + kk2];
                f16x8 ba = bfr[4 + fn * 2 + kk2];
#pragma unroll
                for (int fm = 0; fm < 2; ++fm) {
                    accX[fm][fn] = __builtin_amdgcn_mfma_f32_16x16x32_f16(af[fm], bx, accX[fm][fn], 0, 0, 0);
                    accA[fm][fn] = __builtin_amdgcn_mfma_f32_16x16x32_f16(af[fm], ba, accA[fm][fn], 0, 0, 0);
                }
            }
        }
        // no post-compute barrier: 2-buf rotation + read-complete-before-
        // barrier ordering make next iteration's gl16 overwrite race-free
    }
#undef STAGE_A
#undef LOAD_B

    // ---- xv harvest: slot 7 (= tile n0>>6) lives in buf1; bfr dead here ----
    const f16* As1 = (const f16*)(smem + BUFB);
    f16 xvv[2][2][4];
#pragma unroll
    for (int fn = 0; fn < 2; ++fn) {
        const int ctile = wc * 32 + fn * 16 + (lane & 15);
#pragma unroll
        for (int fm = 0; fm < 2; ++fm)
#pragma unroll
            for (int reg = 0; reg < 4; ++reg) {
                const int rowt = rowb + fm * 16 + reg;
                xvv[fn][fm][reg] = As1[rowt * 64 + (ctile ^ ((rowt & 7) << 3))];
            }
    }
    __syncthreads();   // xv in regs before overlay writes

    // ---- pass A: epilogue math -> packed {om = 1-a, xn} f16x2 in LDS ----
    // C/D layout: col = lane&15, row = (lane>>4)*4 + reg  [m89-verified]
    {
#pragma unroll
        for (int fn = 0; fn < 2; ++fn) {
            const int ctile = wc * 32 + fn * 16 + (lane & 15);
            const int d = h * BW_ + n0 + ctile;
            const float bx = b_in[d];
            const float ba = b_a[d];
            const float mspd = msp2[d];
#pragma unroll
            for (int fm = 0; fm < 2; ++fm) {
#pragma unroll
                for (int reg = 0; reg < 4; ++reg) {
                    const int rowt = rowb + fm * 16 + reg;       // 0..127
                    float gxl = accX[fm][fn][reg] + bx;
                    float gal = accA[fm][fn][reg] + ba;
                    float gx = __builtin_amdgcn_rcpf(1.f + __builtin_amdgcn_exp2f(-gxl * LOG2E));
                    float ga = __builtin_amdgcn_rcpf(1.f + __builtin_amdgcn_exp2f(-gal * LOG2E));
                    float a  = __builtin_amdgcn_exp2f(mspd * ga);
                    float a2 = a * a;                            // = exp(2*log_a)
                    float mult = __builtin_amdgcn_sqrtf(1.f + 1e-6f - a2);
                    float rv = rst_s[rowt];
                    a *= (1.f - rv);
                    mult = rv + (1.f - rv) * mult;
                    float xv = (float)xvv[fn][fm][reg];
                    f16x2 p;
                    p[0] = (f16)(1.f - a);
                    p[1] = (f16)(xv * gx * mult);
                    axn[rowt * 66 + ctile] = p;
                }
            }
        }
    }
    __syncthreads();

    // ---- pass B: per-segment (16-step) summaries; 8 segs x 64 cols ----
    const int col = tid & 63;
    const int seg = tid >> 6;                 // 0..7
    {
        float A = 1.f, yv = 0.f;
#pragma unroll 4
        for (int i = 0; i < 16; ++i) {
            f16x2 v = axn[(seg * 16 + i) * 66 + col];
            float a = 1.f - (float)v[0];
            yv = fmaf(a, yv, (float)v[1]);
            A *= a;
        }
        segA[seg * 72 + col] = A;
        segY[seg * 72 + col] = yv;
    }
    __syncthreads();

    // ---- pass C: carry-in per segment, rewalk, write packed (yloc, apfx) ----
    {
        float cy = 0.f, pA = 1.f;
        for (int s = 0; s < seg; ++s) {
            float As_ = segA[s * 72 + col];
            cy = fmaf(As_, cy, segY[s * 72 + col]);
            pA *= As_;
        }
        float Arun = 1.f, yv = cy;
        const size_t obase = (size_t)(m0 + seg * 16) * D_ + h * BW_ + n0 + col;
#pragma unroll 4
        for (int i = 0; i < 16; ++i) {
            f16x2 v = axn[(seg * 16 + i) * 66 + col];
            float a = 1.f - (float)v[0];
            yv = fmaf(a, yv, (float)v[1]);
            Arun *= a;
            f16x2 p;
            p[0] = (f16)yv;
            p[1] = (f16)(pA * Arun);
            ylap[obase + (size_t)i * D_] = p;
        }
        if (seg == 7) {
            const int bb = m0 >> 11;             // batch
            const int cc = (m0 & 2047) >> 7;     // chunk in batch
            size_t si = ((size_t)bb * NCH + cc) * D_ + h * BW_ + n0 + col;
            sumA[si] = pA * Arun;
            sumY[si] = yv;
        }
    }
}

// ---------- scan apply (carry scan folded in): y = yloc + h0 * apfx ----------
__global__ __launch_bounds__(256)
void scan_apply(const float* __restrict__ sumA, const float* __restrict__ sumY,
                const f16x2* __restrict__ ylap, float* __restrict__ y) {
    const int tid = threadIdx.x;
    const int d4  = (blockIdx.x * 256 + tid) * 4;
    const int c   = blockIdx.y >> 2;
    const int tq  = blockIdx.y & 3;
    const int b   = blockIdx.z;
    f32x4 h0 = {0.f, 0.f, 0.f, 0.f};
    for (int cp = 0; cp < c; ++cp) {
        size_t si = (((size_t)(b * NCH + cp)) << 12) + d4;
        f32x4 A = *(const f32x4*)(sumA + si);
        f32x4 Y = *(const f32x4*)(sumY + si);
        h0.x = fmaf(A.x, h0.x, Y.x);
        h0.y = fmaf(A.y, h0.y, Y.y);
        h0.z = fmaf(A.z, h0.z, Y.z);
        h0.w = fmaf(A.w, h0.w, Y.w);
    }
    size_t base = ((size_t)(b * L_ + c * CHUNK + tq * 32)) * D_ + d4;
#pragma unroll 4
    for (int i = 0; i < 32; ++i) {
        size_t o = base + (size_t)i * D_;
        f16x8 p = *(const f16x8*)(ylap + o);   // [y0,a0,y1,a1,y2,a2,y3,a3]
        f32x4 ov;
        ov.x = fmaf(h0.x, (float)p[1], (float)p[0]);
        ov.y = fmaf(h0.y, (float)p[3], (float)p[2]);
        ov.z = fmaf(h0.z, (float)p[5], (float)p[4]);
        ov.w = fmaf(h0.w, (float)p[7], (float)p[6]);
        *(f32x4*)(y + o) = ov;
    }
}

extern "C" void kernel_launch(void* const* d_in, const int* in_sizes, int n_in,
                              void* d_out, int out_size, void* d_ws, size_t ws_size,
                              hipStream_t stream) {
    const float* x       = (const float*)d_in[0];
    const int*   segpos  = (const int*)d_in[1];
    // d_in[2] = prev_h (unused by reference for L>1 path)
    const float* w_in    = (const float*)d_in[3];
    const float* b_in    = (const float*)d_in[4];
    const float* w_a     = (const float*)d_in[5];
    const float* b_a     = (const float*)d_in[6];
    const float* a_param = (const float*)d_in[7];

    float* y  = (float*)d_out;
    char*  ws = (char*)d_ws;
    f16*   wpk   = (f16*)(ws + OFF_WPK);
    float* msp2  = (float*)(ws + OFF_MSP);
    f16*   xh    = (f16*)(ws + OFF_XH);
    f16x2* ylap  = (f16x2*)(ws + OFF_YLAP);
    float* sumA  = (float*)(ws + OFF_SUMA);
    float* sumY  = (float*)(ws + OFF_SUMY);

    prep_all<<<dim3(3072), 256, 0, stream>>>(w_in, w_a, a_param, x, wpk, msp2, xh);
    gemm_gates<<<dim3(M_ / BM, BW_ / BN, H_), 512, 0, stream>>>(
        xh, segpos, wpk, b_in, b_a, msp2, ylap, sumA, sumY);
    scan_apply<<<dim3(D_ / 1024, NCH * 4, B_), 256, 0, stream>>>(sumA, sumY, ylap, y);
}

// Round 20
// 215.971 us; speedup vs baseline: 1.1669x; 1.1669x over previous
//
#include <hip/hip_runtime.h>
#include <hip/hip_bf16.h>

typedef _Float16 f16;
typedef _Float16 f16x2 __attribute__((ext_vector_type(2)));
typedef _Float16 f16x8 __attribute__((ext_vector_type(8)));
typedef float f32x4 __attribute__((ext_vector_type(4)));

#define B_  4
#define L_  2048
#define D_  4096
#define H_  8
#define BW_ 512
#define M_  (B_*L_)      // 8192
#define CHUNK 128
#define NCH (L_/CHUNK)   // 16
#define LOG2E 1.4426950408889634f

// workspace layout (bytes)
static const size_t OFF_WPK   = 0;                 // packed B frags: 8MB (both gates)
static const size_t OFF_MSP   = 8ull<<20;          // D_ f32, pre-scaled by log2e
static const size_t OFF_XH    = 9ull<<20;          // M*D fp16 = 64MB
static const size_t OFF_YLAP  = 73ull<<20;         // M*D f16x2 (yloc,apfx) = 134MB
static const size_t OFF_SUMA  = 208ull<<20;        // B*NCH*D f32 = 1MB
static const size_t OFF_SUMY  = 209ull<<20;

__device__ __forceinline__ void gl16(const void* g, void* l) {
    __builtin_amdgcn_global_load_lds(
        (const __attribute__((address_space(1))) unsigned int*)g,
        (__attribute__((address_space(3))) unsigned int*)l, 16, 0, 0);
}

// ---------- prep (merged): wpack + msp2 (blocks 0..1023) | x->f16 (1024..3071) ----------
__global__ __launch_bounds__(256)
void prep_all(const float* __restrict__ w_in, const float* __restrict__ w_a,
              const float* __restrict__ a_param, const float* __restrict__ x,
              f16* __restrict__ wpk, float* __restrict__ msp2,
              f16* __restrict__ xh) {
    const int bid = blockIdx.x;
    const int tid = threadIdx.x;
    if (bid < 1024) {
        const int kt  = bid & 7;
        const int n32 = (bid >> 3) & 15;
        const int h   = bid >> 7;
        if (bid < 16) {                    // folded: msp2[d]
            int d = bid * 256 + tid;
            float v = a_param[d];
            msp2[d] = -8.f * log1pf(expf(v)) * LOG2E;
        }
#pragma unroll
        for (int q = 0; q < 2; ++q) {
            int slot = q * 256 + tid;      // 0..511
            int lane = slot & 63;
            int fidx = slot >> 6;          // g*4 + fn*2 + kk2
            int g    = fidx >> 2;
            int fn   = (fidx >> 1) & 1;
            int kk2  = fidx & 1;
            int row = n32 * 32 + fn * 16 + (lane & 15);
            int col = kt * 64 + kk2 * 32 + ((lane >> 4) << 3);
            const float* src = (g ? w_a : w_in) + (size_t)h * BW_ * BW_;
            f16x8 v;
#pragma unroll
            for (int e = 0; e < 8; ++e)
                v[e] = (f16)src[(size_t)(col + e) * BW_ + row];
            size_t o = ((((size_t)(h * 16 + n32) * 8 + kt) * 8) + fidx) * 64 + lane;
            *(f16x8*)(wpk + o * 8) = v;
        }
    } else {
        size_t i = ((size_t)(bid - 1024) * 256 + tid) * 8;
        const size_t stride = (size_t)2048 * 256 * 8;
        for (; i < (size_t)M_ * D_; i += stride) {
            f32x4 v0 = *(const f32x4*)(x + i);
            f32x4 v1 = *(const f32x4*)(x + i + 4);
            f16x8 hv;
            hv[0] = (f16)v0.x; hv[1] = (f16)v0.y; hv[2] = (f16)v0.z; hv[3] = (f16)v0.w;
            hv[4] = (f16)v1.x; hv[5] = (f16)v1.y; hv[6] = (f16)v1.z; hv[7] = (f16)v1.w;
            *(f16x8*)(xh + i) = hv;
        }
    }
}

// ---------- fused gate GEMM + epilogue + chunk-local scan (R16 optimum) ----------
// BM=128 (= one scan chunk), BN=64, BKK=64, NT=8, 4 waves (2x2), 16x16x32 f16.
// K-loop: ONE barrier per tile (3-buf rotation makes the post-compute barrier
// redundant); explicit vmcnt pre-barrier drains only A(t) (issued 2 iters
// ago); B(t+1) issued BEFORE A(t+2) so the implicit wait on B(t) regs leaves
// both prefetches in flight. Epilogue stores {om=1-a, gm=gx*mult}; passes
// B/C read xv from surviving buf0 (tile n0>>6, slot 6 via txo=+2).
#define BM 128
#define BN 64
#define BKK 64
#define NT (BW_/BKK)     // 8 K-tiles
#define BUFB 16384       // bytes per A staging buffer

// LDS: bufs @0/16384/32768 (48K; buf0 SURVIVES for xv).  Post-loop overlay
// (over buf1+buf2 only): axn[128][66] f16x2 {om,gm} @16384 (33792 -> 50176) |
// segA[4][72]f32 @50176 | segY @51328 | rst_s[128]f32 @52480 -> 52992
#define SMEM_BYTES 52992

__global__ __launch_bounds__(256, 2)
void gemm_gates(const f16*   __restrict__ xh,
                const int*   __restrict__ segpos,
                const f16*   __restrict__ wpk,
                const float* __restrict__ b_in,
                const float* __restrict__ b_a,
                const float* __restrict__ msp2,
                f16x2* __restrict__ ylap,
                float* __restrict__ sumA,
                float* __restrict__ sumY) {
    __shared__ __align__(16) char smem[SMEM_BYTES];
    f16x2* axn  = (f16x2*)(smem + 16384);     // [128][66] {om, gm}
    float* segA = (float*)(smem + 50176);     // [4][72]
    float* segY = (float*)(smem + 51328);     // [4][72]
    float* rst_s= (float*)(smem + 52480);     // [128]

    const int tid  = threadIdx.x;
    const int m0   = blockIdx.x * BM;         // m fastest (R6/R12 grid)
    const int n0   = blockIdx.y * BN;
    const int h    = blockIdx.z;
    const int lane = tid & 63;
    const int wid  = tid >> 6;
    const int wr   = wid >> 1;
    const int wc   = wid & 1;

    f32x4 accX[4][2] = {};
    f32x4 accA[4][2] = {};

    // reset flags -> LDS region untouched by staging (visible after barrier 0)
    if (tid < BM) rst_s[tid] = (segpos[m0 + tid] == 0) ? 1.f : 0.f;

    // A staging map (source col pre-swizzled; LDS dest linear — m173/m201)
    const int grow  = lane >> 3;
    const int gcolS = (((lane & 7) ^ grow) << 3);
    const f16* aSrc = xh + (size_t)(m0 + wid * 32 + grow) * D_ + h * BW_ + gcolS;

    // B packed fragment base for this wave: (h, n32 = n0/32 + wc)
    const f16* wbase = wpk + ((size_t)(h * 16) + (n0 >> 5) + wc) * 32768;

    const int swz  = (lane & 7) << 3;        // read-side XOR (involution)
    const int kx   = (lane >> 4) << 3;       // 0,8,16,24
    const int arow = wr * 64 + (lane & 15);
    const int rowb = wr * 64 + ((lane >> 4) << 2);
    const int txo  = ((n0 >> 6) + 2) & (NT - 1); // slot 6 = tile n0>>6 -> buf 0

    f16x8 bfr[2][8];

#define STAGE_A(T)                                                            \
    {                                                                         \
        const int ktg = ((T) + txo) & (NT - 1);                               \
        f16* Asb = (f16*)(smem + ((T) % 3) * BUFB);                           \
        _Pragma("unroll")                                                     \
        for (int q = 0; q < 4; ++q)                                           \
            gl16(aSrc + ktg * BKK + (size_t)q * 8 * D_,                       \
                 &Asb[(wid * 32 + q * 8) * 64]);                              \
    }
#define LOAD_B(T)                                                             \
    {                                                                         \
        const int ktg = ((T) + txo) & (NT - 1);                               \
        const f16* tp = wbase + (size_t)ktg * 4096;                           \
        _Pragma("unroll")                                                     \
        for (int j = 0; j < 8; ++j)                                           \
            bfr[(T) & 1][j] = *(const f16x8*)(tp + j * 512 + lane * 8);       \
    }

    // prologue: B(0) oldest, then A(0), A(1)
    LOAD_B(0);
    STAGE_A(0);
    STAGE_A(1);

#pragma unroll
    for (int t = 0; t < NT; ++t) {
        // explicit pre-barrier wait: drain A(t) (+B(0) at t=0); keep
        // A(t+1)[4] (+B(t)[8] for t>0) in flight
        if (t == 0)          asm volatile("s_waitcnt vmcnt(4)"  ::: "memory");
        else if (t < NT - 1) asm volatile("s_waitcnt vmcnt(12)" ::: "memory");
        else                 asm volatile("s_waitcnt vmcnt(8)"  ::: "memory");
        __builtin_amdgcn_s_barrier();        // all waves' A(t) visible
        // issue next prefetches: B before A (FIFO: implicit wait on B(t)
        // regs then leaves B(t+1)+A(t+2) flying)
        if (t + 1 < NT) LOAD_B(t + 1);       // 8 vm
        if (t + 2 < NT) STAGE_A(t + 2);      // 4 vm
        __builtin_amdgcn_sched_barrier(0);   // pin issues before compute

        const f16* Asb = (const f16*)(smem + (t % 3) * BUFB);
#pragma unroll
        for (int kk2 = 0; kk2 < 2; ++kk2) {
            const int kcolS = (kk2 * 32 + kx) ^ swz;
            f16x8 af[4];
#pragma unroll
            for (int fm = 0; fm < 4; ++fm)
                af[fm] = *(const f16x8*)&Asb[(arow + fm * 16) * 64 + kcolS];
#pragma unroll
            for (int fn = 0; fn < 2; ++fn) {
                f16x8 bx = bfr[t & 1][fn * 2 + kk2];
                f16x8 ba = bfr[t & 1][4 + fn * 2 + kk2];
#pragma unroll
                for (int fm = 0; fm < 4; ++fm) {
                    accX[fm][fn] = __builtin_amdgcn_mfma_f32_16x16x32_f16(af[fm], bx, accX[fm][fn], 0, 0, 0);
                    accA[fm][fn] = __builtin_amdgcn_mfma_f32_16x16x32_f16(af[fm], ba, accA[fm][fn], 0, 0, 0);
                }
            }
        }
        // no second barrier: 3-buf rotation + read-before-MFMA ordering make
        // the next iteration's gl16 overwrite race-free
    }
#undef STAGE_A
#undef LOAD_B

    __syncthreads();   // all compute reads of buf1/buf2 done before overlay

    // ---- pass A: epilogue math -> packed {om = 1-a, gm = gx*mult} in LDS ----
    // C/D layout: col = lane&15, row = (lane>>4)*4 + reg  [m89-verified]
    {
#pragma unroll
        for (int fn = 0; fn < 2; ++fn) {
            const int ctile = wc * 32 + fn * 16 + (lane & 15);
            const int d = h * BW_ + n0 + ctile;
            const float bx = b_in[d];
            const float ba = b_a[d];
            const float mspd = msp2[d];
#pragma unroll
            for (int fm = 0; fm < 4; ++fm) {
#pragma unroll
                for (int reg = 0; reg < 4; ++reg) {
                    const int rowt = rowb + fm * 16 + reg;       // 0..127
                    float gxl = accX[fm][fn][reg] + bx;
                    float gal = accA[fm][fn][reg] + ba;
                    float gx = __builtin_amdgcn_rcpf(1.f + __builtin_amdgcn_exp2f(-gxl * LOG2E));
                    float ga = __builtin_amdgcn_rcpf(1.f + __builtin_amdgcn_exp2f(-gal * LOG2E));
                    float a  = __builtin_amdgcn_exp2f(mspd * ga);
                    float a2 = a * a;                            // = exp(2*log_a)
                    float mult = __builtin_amdgcn_sqrtf(1.f + 1e-6f - a2);
                    float rv = rst_s[rowt];
                    a *= (1.f - rv);
                    mult = rv + (1.f - rv) * mult;
                    f16x2 p;
                    p[0] = (f16)(1.f - a);
                    p[1] = (f16)(gx * mult);
                    axn[rowt * 66 + ctile] = p;
                }
            }
        }
    }
    __syncthreads();

    // ---- pass B: per-segment (32-step) summaries; xv from surviving buf0 ----
    const f16* As0 = (const f16*)smem;        // tile n0>>6: cols [n0, n0+64)
    const int col = tid & 63;
    const int seg = tid >> 6;
    {
        float A = 1.f, yv = 0.f;
#pragma unroll 4
        for (int i = 0; i < 32; ++i) {
            const int t = seg * 32 + i;
            f16x2 v = axn[t * 66 + col];
            float a  = 1.f - (float)v[0];
            float xv = (float)As0[t * 64 + (col ^ ((t & 7) << 3))];
            yv = fmaf(a, yv, xv * (float)v[1]);
            A *= a;
        }
        segA[seg * 72 + col] = A;
        segY[seg * 72 + col] = yv;
    }
    __syncthreads();

    // ---- pass C: carry-in per segment, rewalk, write packed (yloc, apfx) ----
    {
        float cy = 0.f, pA = 1.f;
        for (int s = 0; s < seg; ++s) {
            float As_ = segA[s * 72 + col];
            cy = fmaf(As_, cy, segY[s * 72 + col]);
            pA *= As_;
        }
        float Arun = 1.f, yv = cy;
        const size_t obase = (size_t)(m0 + seg * 32) * D_ + h * BW_ + n0 + col;
#pragma unroll 4
        for (int i = 0; i < 32; ++i) {
            const int t = seg * 32 + i;
            f16x2 v = axn[t * 66 + col];
            float a  = 1.f - (float)v[0];
            float xv = (float)As0[t * 64 + (col ^ ((t & 7) << 3))];
            yv = fmaf(a, yv, xv * (float)v[1]);
            Arun *= a;
            f16x2 p;
            p[0] = (f16)yv;
            p[1] = (f16)(pA * Arun);
            ylap[obase + (size_t)i * D_] = p;
        }
        if (seg == 3) {
            const int bb = m0 >> 11;             // batch
            const int cc = (m0 & 2047) >> 7;     // chunk in batch
            size_t si = ((size_t)bb * NCH + cc) * D_ + h * BW_ + n0 + col;
            sumA[si] = pA * Arun;
            sumY[si] = yv;
        }
    }
}

// ---------- scan apply (carry scan folded in): y = yloc + h0 * apfx ----------
__global__ __launch_bounds__(256)
void scan_apply(const float* __restrict__ sumA, const float* __restrict__ sumY,
                const f16x2* __restrict__ ylap, float* __restrict__ y) {
    const int tid = threadIdx.x;
    const int d4  = (blockIdx.x * 256 + tid) * 4;
    const int c   = blockIdx.y >> 2;
    const int tq  = blockIdx.y & 3;
    const int b   = blockIdx.z;
    f32x4 h0 = {0.f, 0.f, 0.f, 0.f};
    for (int cp = 0; cp < c; ++cp) {
        size_t si = (((size_t)(b * NCH + cp)) << 12) + d4;
        f32x4 A = *(const f32x4*)(sumA + si);
        f32x4 Y = *(const f32x4*)(sumY + si);
        h0.x = fmaf(A.x, h0.x, Y.x);
        h0.y = fmaf(A.y, h0.y, Y.y);
        h0.z = fmaf(A.z, h0.z, Y.z);
        h0.w = fmaf(A.w, h0.w, Y.w);
    }
    size_t base = ((size_t)(b * L_ + c * CHUNK + tq * 32)) * D_ + d4;
#pragma unroll 4
    for (int i = 0; i < 32; ++i) {
        size_t o = base + (size_t)i * D_;
        f16x8 p = *(const f16x8*)(ylap + o);   // [y0,a0,y1,a1,y2,a2,y3,a3]
        f32x4 ov;
        ov.x = fmaf(h0.x, (float)p[1], (float)p[0]);
        ov.y = fmaf(h0.y, (float)p[3], (float)p[2]);
        ov.z = fmaf(h0.z, (float)p[5], (float)p[4]);
        ov.w = fmaf(h0.w, (float)p[7], (float)p[6]);
        *(f32x4*)(y + o) = ov;
    }
}

extern "C" void kernel_launch(void* const* d_in, const int* in_sizes, int n_in,
                              void* d_out, int out_size, void* d_ws, size_t ws_size,
                              hipStream_t stream) {
    const float* x       = (const float*)d_in[0];
    const int*   segpos  = (const int*)d_in[1];
    // d_in[2] = prev_h (unused by reference for L>1 path)
    const float* w_in    = (const float*)d_in[3];
    const float* b_in    = (const float*)d_in[4];
    const float* w_a     = (const float*)d_in[5];
    const float* b_a     = (const float*)d_in[6];
    const float* a_param = (const float*)d_in[7];

    float* y  = (float*)d_out;
    char*  ws = (char*)d_ws;
    f16*   wpk   = (f16*)(ws + OFF_WPK);
    float* msp2  = (float*)(ws + OFF_MSP);
    f16*   xh    = (f16*)(ws + OFF_XH);
    f16x2* ylap  = (f16x2*)(ws + OFF_YLAP);
    float* sumA  = (float*)(ws + OFF_SUMA);
    float* sumY  = (float*)(ws + OFF_SUMY);

    prep_all<<<dim3(3072), 256, 0, stream>>>(w_in, w_a, a_param, x, wpk, msp2, xh);
    gemm_gates<<<dim3(M_ / BM, BW_ / BN, H_), 256, 0, stream>>>(
        xh, segpos, wpk, b_in, b_a, msp2, ylap, sumA, sumY);
    scan_apply<<<dim3(D_ / 1024, NCH * 4, B_), 256, 0, stream>>>(sumA, sumY, ylap, y);
}